// Round 18
// baseline (507.631 us; speedup 1.0000x reference)
//
#include <hip/hip_runtime.h>

#define NN   50000
#define NPAD 50048           // 391 * 128
#define EE   600000
#define DD   128
#define HH   256
#define KX   96              // padded K for x-projection (78 -> 96)
#define LL   5
#define BN_EPS 1e-5f
#define SCAN_BLOCKS 196      // ceil(NN/256)

typedef _Float16 f16x8 __attribute__((ext_vector_type(8)));
typedef _Float16 f16x2 __attribute__((ext_vector_type(2)));
typedef float    f32x4 __attribute__((ext_vector_type(4)));

union U32F16 { unsigned int u; _Float16 h[2]; };
union U32H2  { unsigned int u; f16x2 v; };

// ---------------- fused prep: conversions + zeroing (one dispatch) ----------------
// W1T: one pre-swizzled 64KB image per layer (256 rows x 256B, byte ^= (row&7)<<4).
// W2T: TWO pre-swizzled 32KB K-half images per layer (128 rows x 256B each).
#define R0 (NPAD * KX)
#define R1 (R0 + DD * KX)
#define R2 (R1 + LL * DD * HH)
#define R3 (R2 + 50048)
#define R4 (R3 + LL * 256)
#define R5 (R4 + 3072)       // aggH pad rows
#define R6 (R5 + 256)        // scan lookback flags
__global__ void prep_kernel(const float* __restrict__ x, const float* __restrict__ Wx,
                            const float* __restrict__ W1, const float* __restrict__ W2,
                            _Float16* __restrict__ xH, _Float16* __restrict__ WxT,
                            char* __restrict__ W1T, char* __restrict__ W2T,
                            int* __restrict__ counts, float* __restrict__ sumsL,
                            _Float16* __restrict__ aggH, int* __restrict__ post)
{
    int idx = blockIdx.x * 256 + threadIdx.x;
    if (idx < R0) {
        int n = idx / KX, k = idx % KX;
        float v = (n < NN && k < 78) ? x[(size_t)n * 78 + k] : 0.f;
        xH[idx] = (_Float16)v;
    } else if (idx < R1) {
        int r = idx - R0;
        int d = r / KX, k = r % KX;
        WxT[r] = (_Float16)((k < 78) ? Wx[(size_t)k * DD + d] : 0.f);
    } else if (idx < R2) {
        int r0 = idx - R1;
        int l = r0 / (DD * HH), r = r0 % (DD * HH);
        int k1 = r / HH, n1 = r % HH;                       // W1 [l][k(128)][n(256)]
        unsigned int b1o = ((unsigned int)(n1 * 256 + k1 * 2)) ^ (((unsigned int)(n1 & 7)) << 4);
        *(_Float16*)(W1T + (size_t)l * 65536 + b1o) = (_Float16)W1[r0];
        int k2 = r / DD, n2 = r % DD;                       // W2 [l][k(256)][n(128)]
        int h2 = k2 >> 7, kk = k2 & 127;                    // K-half images
        unsigned int b2o = ((unsigned int)(n2 * 256 + kk * 2)) ^ (((unsigned int)(n2 & 7)) << 4);
        *(_Float16*)(W2T + (size_t)l * 65536 + h2 * 32768 + b2o) = (_Float16)W2[r0];
    } else if (idx < R3) {
        counts[idx - R2] = 0;
    } else if (idx < R4) {
        sumsL[idx - R3] = 0.f;
    } else if (idx < R5) {
        ((unsigned int*)(aggH + (size_t)NN * DD))[idx - R4] = 0u;
    } else if (idx < R6) {
        post[idx - R5] = 0;
    }
}

// ------------- edge counts (int atomics only) -------------
__global__ void count_kernel(const int* __restrict__ ei, int* __restrict__ counts)
{
    int e = blockIdx.x * 256 + threadIdx.x;
    if (e >= EE) return;
    atomicAdd(&counts[ei[EE + e]], 1);
}

// ---------------- single-pass exclusive scan (decoupled lookback) ----------------
// post[b] holds (inclusive_prefix_through_block_b + 1); 0 = not ready.
// 196 blocks <= 256 CUs -> all co-resident, spin is deadlock-free; integer sums
// are deterministic regardless of arrival order.
__global__ __launch_bounds__(256) void scan_kernel(
    const int* __restrict__ counts, int* __restrict__ rowptr,
    int* __restrict__ cursor, int* __restrict__ post)
{
    __shared__ int buf[256];
    __shared__ int s_prev;
    const int b = blockIdx.x;
    const int i = b * 256 + threadIdx.x;
    int v = (i < NN) ? counts[i] : 0;
    int val = v;
    buf[threadIdx.x] = val;
    __syncthreads();
    for (int off = 1; off < 256; off <<= 1) {
        int t = (threadIdx.x >= off) ? buf[threadIdx.x - off] : 0;
        __syncthreads();
        val += t;
        buf[threadIdx.x] = val;
        __syncthreads();
    }
    if (threadIdx.x == 255) {
        int prev = 0;
        if (b > 0) {
            int f;
            do { f = atomicAdd(&post[b - 1], 0); } while (f == 0);
            prev = f - 1;
        }
        atomicExch(&post[b], prev + val + 1);   // val == block total here (thread 255)
        s_prev = prev;
    }
    __syncthreads();
    int r = s_prev + val - v;                    // global exclusive prefix
    if (i < NN) {
        rowptr[i] = r;
        cursor[i] = r;
    } else if (i == NN) {
        rowptr[NN] = r;                          // == EE
    }
}

__global__ void csr_fill_kernel(const int* __restrict__ ei, int* __restrict__ cursor,
                                int2* __restrict__ csr)
{
    int e = blockIdx.x * 256 + threadIdx.x;
    if (e >= EE) return;
    int dst = ei[EE + e];
    int pos = atomicAdd(&cursor[dst], 1);
    csr[pos] = make_int2(ei[e], e);     // {src, eid} one 8B store
}

// -------- per-node edge-attr sums + degree: s7[n][0..6], s7[n][7]=deg --------
__global__ __launch_bounds__(256) void node_prep_kernel(
    const float* __restrict__ ea, const int* __restrict__ rowptr,
    const int2* __restrict__ csr, float* __restrict__ s7)
{
    int n = blockIdx.x * 4 + (threadIdx.x >> 6);
    int lane = threadIdx.x & 63;
    if (n >= NN) return;
    int beg = rowptr[n], end = rowptr[n + 1];
    int j = lane >> 3, k = lane & 7;
    float s = 0.f;
    if (k < 7) {
        for (int base = beg; base < end; base += 8) {
            int e_i = base + j;
            if (e_i < end) s += ea[(size_t)csr[e_i].y * 7 + k];
        }
    }
    s += __shfl_xor(s, 8);
    s += __shfl_xor(s, 16);
    s += __shfl_xor(s, 32);
    if (lane < 7)      s7[n * 8 + lane] = s;
    else if (lane == 7) s7[n * 8 + 7] = (float)(end - beg);
}

// --------- aggregation v4: packed-f16 BN+ReLU+accumulate ---------
template<int APPLYBN>
__global__ __launch_bounds__(256) void aggregate_kernel(
    const _Float16* __restrict__ zin, const int* __restrict__ rowptr,
    const int2* __restrict__ csr, const float* __restrict__ s7,
    const float* __restrict__ We, const float* __restrict__ be,
    const float* __restrict__ sums, const float* __restrict__ gamma,
    const float* __restrict__ beta, _Float16* __restrict__ aggH)
{
    __shared__ float sWe[7 * DD];
    for (int i = threadIdx.x; i < 7 * DD; i += 256) sWe[i] = We[i];
    __syncthreads();
    const int lane = threadIdx.x & 63;
    const int li = lane & 15;               // 16 lanes per node
    const int n = blockIdx.x * 16 + ((threadIdx.x >> 6) << 2) + (lane >> 4);
    const int d0 = li * 8;                  // dims d0..d0+7
    f16x2 Ah[4], Ch[4];
    const f16x2 zero2 = {(_Float16)0.f, (_Float16)0.f};
    if (APPLYBN) {
        const float invN = 1.0f / NN;
#pragma unroll
        for (int q = 0; q < 4; q++) {
#pragma unroll
            for (int s = 0; s < 2; s++) {
                int d = d0 + 2 * q + s;
                float mu = sums[d] * invN;
                float var = fmaf(-mu, mu, sums[DD + d] * invN);
                float a = gamma[d] * rsqrtf(var + BN_EPS);
                float c = fmaf(-mu, a, beta[d]);
                Ah[q][s] = (_Float16)a;
                Ch[q][s] = (_Float16)c;
            }
        }
    }
    const uint4* z4 = (const uint4*)zin;    // row = 16 uint4 chunks
    int beg = rowptr[n], end = rowptr[n + 1];
    f16x2 acch[4] = {zero2, zero2, zero2, zero2};
#define ACCU(uu) { U32H2 p0, p1, p2, p3; \
    p0.u = (uu).x; p1.u = (uu).y; p2.u = (uu).z; p3.u = (uu).w; \
    if (APPLYBN) { \
        acch[0] += __builtin_elementwise_max(Ah[0] * p0.v + Ch[0], zero2); \
        acch[1] += __builtin_elementwise_max(Ah[1] * p1.v + Ch[1], zero2); \
        acch[2] += __builtin_elementwise_max(Ah[2] * p2.v + Ch[2], zero2); \
        acch[3] += __builtin_elementwise_max(Ah[3] * p3.v + Ch[3], zero2); \
    } else { \
        acch[0] += p0.v; acch[1] += p1.v; acch[2] += p2.v; acch[3] += p3.v; \
    } }
    int i = beg;
    for (; i + 8 <= end; i += 8) {
        uint4 u[8];
#pragma unroll
        for (int t = 0; t < 8; t++)
            u[t] = z4[(size_t)csr[i + t].x * 16 + li];
#pragma unroll
        for (int t = 0; t < 8; t++) ACCU(u[t])
    }
    for (; i + 4 <= end; i += 4) {
        uint4 u[4];
#pragma unroll
        for (int t = 0; t < 4; t++)
            u[t] = z4[(size_t)csr[i + t].x * 16 + li];
#pragma unroll
        for (int t = 0; t < 4; t++) ACCU(u[t])
    }
    for (; i < end; i++) {
        uint4 u = z4[(size_t)csr[i].x * 16 + li];
        ACCU(u)
    }
#undef ACCU
    float dg = s7[n * 8 + 7];
    float r[8];
#pragma unroll
    for (int q = 0; q < 4; q++) {
        r[2 * q]     = fmaf(dg, be[d0 + 2 * q],     (float)acch[q][0]);
        r[2 * q + 1] = fmaf(dg, be[d0 + 2 * q + 1], (float)acch[q][1]);
    }
#pragma unroll
    for (int k = 0; k < 7; k++) {
        float sv = s7[n * 8 + k];
#pragma unroll
        for (int t = 0; t < 8; t++) r[t] = fmaf(sv, sWe[k * DD + d0 + t], r[t]);
    }
    uint4 o;
    U32F16 p0, p1, p2, p3;
    p0.h[0] = (_Float16)r[0]; p0.h[1] = (_Float16)r[1];
    p1.h[0] = (_Float16)r[2]; p1.h[1] = (_Float16)r[3];
    p2.h[0] = (_Float16)r[4]; p2.h[1] = (_Float16)r[5];
    p3.h[0] = (_Float16)r[6]; p3.h[1] = (_Float16)r[7];
    o.x = p0.u; o.y = p1.u; o.z = p2.u; o.w = p3.u;
    ((uint4*)aggH)[(size_t)n * 16 + li] = o;
}

// ---------------- fused MLP v3f: 512 thr / 8 waves, 128 rows/block, grid=391 ----------------
// Dual-prefetch + half-pipeline + swapped-operand GEMM1 + A-frags hoisted pre-barrier.
__global__ __launch_bounds__(512) void mlp_fused3(
    const _Float16* __restrict__ A, const char* __restrict__ W1T_l,
    const float* __restrict__ b1l, const char* __restrict__ W2T_l,
    const float* __restrict__ b2l, _Float16* __restrict__ Z,
    float* __restrict__ sums)
{
    __shared__ __align__(16) char W1s[65536];   // 256 rows x 256B, swz
    __shared__ __align__(16) char W2s[32768];   // 128 rows x 256B (one K-half), swz
    __shared__ __align__(16) char Hid[32768];   // 128 rows x 128 cols f16 (one half), swz
    __shared__ float red[8][2][128];
    const int tid = threadIdx.x, lane = tid & 63, wid = tid >> 6;   // 8 waves
    const int lr = lane & 15, kg = lane >> 4;
    const int rowA = blockIdx.x * 128 + wid * 16;

    // ---- upfront async staging: W1 full (8/wave) + W2 K-half0 (4/wave) ----
#pragma unroll
    for (int i = 0; i < 8; i++) {
        int chunk = wid * 8192 + i * 1024;
        __builtin_amdgcn_global_load_lds(
            (const __attribute__((address_space(1))) unsigned int*)(W1T_l + chunk + lane * 16),
            (__attribute__((address_space(3))) unsigned int*)(W1s + chunk),
            16, 0, 0);
    }
#pragma unroll
    for (int i = 0; i < 4; i++) {
        int chunk = wid * 4096 + i * 1024;
        __builtin_amdgcn_global_load_lds(
            (const __attribute__((address_space(1))) unsigned int*)(W2T_l + chunk + lane * 16),
            (__attribute__((address_space(3))) unsigned int*)(W2s + chunk),
            16, 0, 0);
    }

    // ---- A-frags issued BEFORE the barrier: latency hides under staging drain ----
    f16x8 a[4];
    const _Float16* Ap = A + (size_t)(rowA + lr) * DD + kg * 8;
#pragma unroll
    for (int ks = 0; ks < 4; ks++) a[ks] = *(const f16x8*)(Ap + ks * 32);

    __syncthreads();

    const int r = wid * 16 + lr;                 // hidden row (block-local)
    const int rswz = (r & 7) << 4;
    f32x4 acc2[8] = {};
#pragma unroll
    for (int h = 0; h < 2; h++) {
        // ---- GEMM1 half h (swapped operands): Hid[r][0..127] = relu(A @ W1h + b1h) ----
#pragma unroll
        for (int gq = 0; gq < 2; gq++) {
            f32x4 acc[4] = {};
#pragma unroll
            for (int ks = 0; ks < 4; ks++) {
#pragma unroll
                for (int g = 0; g < 4; g++) {
                    int row = h * 128 + gq * 64 + g * 16 + lr;
                    int byteo = (row * 256 + ks * 64 + kg * 16) ^ ((row & 7) << 4);
                    f16x8 b = *(const f16x8*)(W1s + byteo);
                    acc[g] = __builtin_amdgcn_mfma_f32_16x16x32_f16(b, a[ks], acc[g], 0, 0, 0);
                }
            }
#pragma unroll
            for (int g = 0; g < 4; g++) {
                int lcol = gq * 64 + g * 16 + kg * 4;      // col within half
                float4 bv = *(const float4*)(b1l + h * 128 + lcol);
                U32F16 p0, p1;
                p0.h[0] = (_Float16)fmaxf(acc[g][0] + bv.x, 0.f);
                p0.h[1] = (_Float16)fmaxf(acc[g][1] + bv.y, 0.f);
                p1.h[0] = (_Float16)fmaxf(acc[g][2] + bv.z, 0.f);
                p1.h[1] = (_Float16)fmaxf(acc[g][3] + bv.w, 0.f);
                int byteo = (r * 256 + lcol * 2) ^ rswz;
                uint2 w; w.x = p0.u; w.y = p1.u;
                *(uint2*)(Hid + byteo) = w;
            }
        }
        __syncthreads();   // Hid ready; (h==1) also drains W2-half1 staging

        // ---- GEMM2 partial-K: acc2 += Hid_h @ W2_Kh ----
#pragma unroll
        for (int ks = 0; ks < 4; ks++) {
            int hb = (r * 256 + ks * 64 + kg * 16) ^ rswz;
            f16x8 a2 = *(const f16x8*)(Hid + hb);
#pragma unroll
            for (int g = 0; g < 8; g++) {
                int row = g * 16 + lr;
                int wb = (row * 256 + ks * 64 + kg * 16) ^ ((row & 7) << 4);
                f16x8 b = *(const f16x8*)(W2s + wb);
                acc2[g] = __builtin_amdgcn_mfma_f32_16x16x32_f16(a2, b, acc2[g], 0, 0, 0);
            }
        }
        if (h == 0) {
            __syncthreads();   // GEMM2h0 done reading W2s + Hid
            // issue W2 K-half1 staging; flies under GEMM1-half1 (drained at its barrier)
#pragma unroll
            for (int i = 0; i < 4; i++) {
                int chunk = wid * 4096 + i * 1024;
                __builtin_amdgcn_global_load_lds(
                    (const __attribute__((address_space(1))) unsigned int*)(W2T_l + 32768 + chunk + lane * 16),
                    (__attribute__((address_space(3))) unsigned int*)(W2s + chunk),
                    16, 0, 0);
            }
        }
    }

    // ---- epilogue: bias, stats, direct f16 stores (no pack shfls) ----
    float sp[8] = {}, sq[8] = {};
#pragma unroll
    for (int g = 0; g < 8; g++) {
        int col = g * 16 + lr;
        float bv = b2l[col];
        int rbase = rowA + kg * 4;
#pragma unroll
        for (int j = 0; j < 4; j++) {
            float v = acc2[g][j] + bv;
            float keep = (rbase + j < NN) ? 1.f : 0.f;
            sp[g] = fmaf(v, keep, sp[g]);
            sq[g] = fmaf(v * v, keep, sq[g]);
            Z[(size_t)(rbase + j) * DD + col] = (_Float16)v;
        }
    }
#pragma unroll
    for (int g = 0; g < 8; g++) {
        sp[g] += __shfl_xor(sp[g], 16); sp[g] += __shfl_xor(sp[g], 32);
        sq[g] += __shfl_xor(sq[g], 16); sq[g] += __shfl_xor(sq[g], 32);
    }
    if (lane < 16) {
#pragma unroll
        for (int g = 0; g < 8; g++) {
            red[wid][0][g * 16 + lr] = sp[g];
            red[wid][1][g * 16 + lr] = sq[g];
        }
    }
    __syncthreads();
    if (tid < 128) {
        float s = 0.f, s2 = 0.f;
#pragma unroll
        for (int w = 0; w < 8; w++) { s += red[w][0][tid]; s2 += red[w][1][tid]; }
        atomicAdd(&sums[tid], s);
        atomicAdd(&sums[DD + tid], s2);
    }
}

// ---------------- f16 MFMA GEMM (projection only) ----------------
template<int K, int Nn>
__global__ __launch_bounds__(256) void gemm_f16(const _Float16* __restrict__ A,
    const _Float16* __restrict__ BT, const float* __restrict__ bias,
    _Float16* __restrict__ C)
{
    const int tid = threadIdx.x;
    const int lane = tid & 63, wid = tid >> 6;
    const int wm = wid >> 1, wn = wid & 1;
    const int row0 = blockIdx.x * 128 + wm * 64;
    const int col0 = blockIdx.y * 64 + wn * 32;
    const int lr = lane & 15, lk = (lane >> 4) * 8;
    f32x4 acc[4][2] = {};
    const _Float16* Ap = A + (size_t)(row0 + lr) * K + lk;
    const _Float16* Bp = BT + (size_t)(col0 + lr) * K + lk;
#pragma unroll
    for (int ks = 0; ks < K; ks += 32) {
        f16x8 a[4], b[2];
#pragma unroll
        for (int f = 0; f < 4; f++) a[f] = *(const f16x8*)(Ap + (size_t)f * 16 * K + ks);
#pragma unroll
        for (int g = 0; g < 2; g++) b[g] = *(const f16x8*)(Bp + (size_t)g * 16 * K + ks);
#pragma unroll
        for (int f = 0; f < 4; f++)
#pragma unroll
            for (int g = 0; g < 2; g++)
                acc[f][g] = __builtin_amdgcn_mfma_f32_16x16x32_f16(a[f], b[g], acc[f][g], 0, 0, 0);
    }
#pragma unroll
    for (int f = 0; f < 4; f++)
#pragma unroll
        for (int g = 0; g < 2; g++) {
            int col = col0 + g * 16 + lr;
            float bv = bias[col];
            int rbase = row0 + f * 16 + (lane >> 4) * 4;
#pragma unroll
            for (int j = 0; j < 4; j++)
                C[(size_t)(rbase + j) * Nn + col] = (_Float16)(acc[f][g][j] + bv);
        }
}

// ---------------- final BN apply -> f32 d_out ----------------
__global__ void bn_apply_kernel(const _Float16* __restrict__ z, const float* __restrict__ sums,
                                const float* __restrict__ gamma, const float* __restrict__ beta,
                                float* __restrict__ outF)
{
    int idx = blockIdx.x * 256 + threadIdx.x;   // over NN*64 u32 pairs
    if (idx >= NN * 64) return;
    int li = idx & 63;
    int d0 = 2 * li, d1 = d0 + 1;
    const float invN = 1.0f / NN;
    float mu0 = sums[d0] * invN, mu1 = sums[d1] * invN;
    float var0 = fmaf(-mu0, mu0, sums[DD + d0] * invN);
    float var1 = fmaf(-mu1, mu1, sums[DD + d1] * invN);
    float i0 = rsqrtf(var0 + BN_EPS), i1 = rsqrtf(var1 + BN_EPS);
    float a0 = gamma[d0] * i0, a1 = gamma[d1] * i1;
    float c0 = fmaf(-mu0, a0, beta[d0]), c1 = fmaf(-mu1, a1, beta[d1]);
    U32F16 u; u.u = ((const unsigned int*)z)[idx];
    int n = idx >> 6;
    float2 o = make_float2(fmaf(a0, (float)u.h[0], c0), fmaf(a1, (float)u.h[1], c1));
    *(float2*)(outF + (size_t)n * DD + d0) = o;
}

// ---------------------------------------------------------------------------
extern "C" void kernel_launch(void* const* d_in, const int* in_sizes, int n_in,
                              void* d_out, int out_size, void* d_ws, size_t ws_size,
                              hipStream_t stream)
{
    const float* x     = (const float*)d_in[0];
    const float* ea    = (const float*)d_in[1];
    const float* Wx    = (const float*)d_in[2];
    const float* bx    = (const float*)d_in[3];
    const float* We    = (const float*)d_in[4];
    const float* be    = (const float*)d_in[5];
    const float* W1    = (const float*)d_in[6];
    const float* b1    = (const float*)d_in[7];
    const float* W2    = (const float*)d_in[8];
    const float* b2    = (const float*)d_in[9];
    const float* gamma = (const float*)d_in[10];
    const float* beta  = (const float*)d_in[11];
    const int*   ei    = (const int*)d_in[12];

    // ---- workspace layout ----
    char* base = (char*)d_ws;
    size_t off = 0;
    auto alloc = [&](size_t bytes) { void* p = base + off; off += (bytes + 15) & ~(size_t)15; return p; };
    _Float16* h16  = (_Float16*)alloc((size_t)NPAD * DD * 2);   // proj output (layer-0 input)
    _Float16* aggH = (_Float16*)alloc((size_t)NPAD * DD * 2);
    _Float16* z16  = (_Float16*)alloc((size_t)NPAD * DD * 2);   // raw MLP output (pre-BN)
    _Float16* xH   = (_Float16*)alloc((size_t)NPAD * KX * 2);
    _Float16* WxT  = (_Float16*)alloc((size_t)DD * KX * 2);
    char*     W1T  = (char*)    alloc((size_t)LL * 65536);      // pre-swizzled LDS images
    char*     W2T  = (char*)    alloc((size_t)LL * 65536);      // 2 x 32KB K-half images/layer
    float*    s7   = (float*)   alloc((size_t)NN * 8 * 4);
    float*    sumsL= (float*)   alloc((size_t)LL * 256 * 4);    // per-layer BN sums
    int* counts    = (int*)alloc(50048 * 4);
    int* rowptr    = (int*)alloc(50056 * 4);
    int* cursor    = (int*)alloc(50048 * 4);
    int* post      = (int*)alloc(256 * 4);                      // scan lookback flags
    int2* csr      = (int2*)alloc((size_t)EE * 8);
    if (ws_size < off) return;

    // ---- prolog (prep fuses all conversions + zeroing, incl. scan flags) ----
    prep_kernel<<<(R6 + 255) / 256, 256, 0, stream>>>(
        x, Wx, W1, W2, xH, WxT, W1T, W2T, counts, sumsL, aggH, post);
    gemm_f16<KX, DD><<<dim3(NPAD / 128, DD / 64), 256, 0, stream>>>(xH, WxT, bx, h16);
    count_kernel<<<(EE + 255) / 256, 256, 0, stream>>>(ei, counts);
    scan_kernel<<<SCAN_BLOCKS, 256, 0, stream>>>(counts, rowptr, cursor, post);
    csr_fill_kernel<<<(EE + 255) / 256, 256, 0, stream>>>(ei, cursor, csr);
    node_prep_kernel<<<(NN + 3) / 4, 256, 0, stream>>>(ea, rowptr, csr, s7);

    // ---- layers ----
    for (int l = 0; l < LL; l++) {
        if (l == 0)
            aggregate_kernel<0><<<NN / 16, 256, 0, stream>>>(
                h16, rowptr, csr, s7, We, be, nullptr, nullptr, nullptr, aggH);
        else
            aggregate_kernel<1><<<NN / 16, 256, 0, stream>>>(
                z16, rowptr, csr, s7, We, be, sumsL + (size_t)(l - 1) * 256,
                gamma + (size_t)(l - 1) * DD, beta + (size_t)(l - 1) * DD, aggH);
        mlp_fused3<<<NPAD / 128, 512, 0, stream>>>(
            aggH, W1T + (size_t)l * 65536, b1 + (size_t)l * HH,
            W2T + (size_t)l * 65536, b2 + (size_t)l * DD, z16,
            sumsL + (size_t)l * 256);
    }
    bn_apply_kernel<<<(NN * 64 + 255) / 256, 256, 0, stream>>>(
        z16, sumsL + (size_t)(LL - 1) * 256, gamma + (size_t)(LL - 1) * DD,
        beta + (size_t)(LL - 1) * DD, (float*)d_out);
}

// Round 19
// 399.796 us; speedup vs baseline: 1.2697x; 1.2697x over previous
//
#include <hip/hip_runtime.h>

#define NN   50000
#define NPAD 50048           // 391 * 128
#define EE   600000
#define DD   128
#define HH   256
#define KX   96              // padded K for x-projection (78 -> 96)
#define LL   5
#define BN_EPS 1e-5f
#define SCAN_BLOCKS 196      // ceil(NN/256)

typedef _Float16 f16x8 __attribute__((ext_vector_type(8)));
typedef _Float16 f16x2 __attribute__((ext_vector_type(2)));
typedef float    f32x4 __attribute__((ext_vector_type(4)));

union U32F16 { unsigned int u; _Float16 h[2]; };
union U32H2  { unsigned int u; f16x2 v; };

// ---------------- fused prep: conversions + zeroing (one dispatch) ----------------
// W1T: one pre-swizzled 64KB image per layer (256 rows x 256B, byte ^= (row&7)<<4).
// W2T: TWO pre-swizzled 32KB K-half images per layer (128 rows x 256B each) so the
// MLP kernel can stage half0 upfront and half1 overlapped with GEMM1-half1.
#define R0 (NPAD * KX)
#define R1 (R0 + DD * KX)
#define R2 (R1 + LL * DD * HH)
#define R3 (R2 + 50048)
#define R4 (R3 + LL * 256)
#define R5 (R4 + 3072)
__global__ void prep_kernel(const float* __restrict__ x, const float* __restrict__ Wx,
                            const float* __restrict__ W1, const float* __restrict__ W2,
                            _Float16* __restrict__ xH, _Float16* __restrict__ WxT,
                            char* __restrict__ W1T, char* __restrict__ W2T,
                            int* __restrict__ counts, float* __restrict__ sumsL,
                            _Float16* __restrict__ aggH)
{
    int idx = blockIdx.x * 256 + threadIdx.x;
    if (idx < R0) {
        int n = idx / KX, k = idx % KX;
        float v = (n < NN && k < 78) ? x[(size_t)n * 78 + k] : 0.f;
        xH[idx] = (_Float16)v;
    } else if (idx < R1) {
        int r = idx - R0;
        int d = r / KX, k = r % KX;
        WxT[r] = (_Float16)((k < 78) ? Wx[(size_t)k * DD + d] : 0.f);
    } else if (idx < R2) {
        int r0 = idx - R1;
        int l = r0 / (DD * HH), r = r0 % (DD * HH);
        int k1 = r / HH, n1 = r % HH;                       // W1 [l][k(128)][n(256)]
        unsigned int b1o = ((unsigned int)(n1 * 256 + k1 * 2)) ^ (((unsigned int)(n1 & 7)) << 4);
        *(_Float16*)(W1T + (size_t)l * 65536 + b1o) = (_Float16)W1[r0];
        int k2 = r / DD, n2 = r % DD;                       // W2 [l][k(256)][n(128)]
        int h2 = k2 >> 7, kk = k2 & 127;                    // K-half images
        unsigned int b2o = ((unsigned int)(n2 * 256 + kk * 2)) ^ (((unsigned int)(n2 & 7)) << 4);
        *(_Float16*)(W2T + (size_t)l * 65536 + h2 * 32768 + b2o) = (_Float16)W2[r0];
    } else if (idx < R3) {
        counts[idx - R2] = 0;
    } else if (idx < R4) {
        sumsL[idx - R3] = 0.f;
    } else if (idx < R5) {
        ((unsigned int*)(aggH + (size_t)NN * DD))[idx - R4] = 0u;
    }
}

// ------------- edge counts (int atomics only) -------------
__global__ void count_kernel(const int* __restrict__ ei, int* __restrict__ counts)
{
    int e = blockIdx.x * 256 + threadIdx.x;
    if (e >= EE) return;
    atomicAdd(&counts[ei[EE + e]], 1);
}

// ---------------- 3-phase exclusive scan for CSR rowptr ----------------
__global__ void count_scan1(const int* __restrict__ counts, int* __restrict__ rowptr,
                            int* __restrict__ blocksums)
{
    __shared__ int buf[256];
    int i = blockIdx.x * 256 + threadIdx.x;
    int v = (i < NN) ? counts[i] : 0;
    int val = v;
    buf[threadIdx.x] = val;
    __syncthreads();
    for (int off = 1; off < 256; off <<= 1) {
        int t = (threadIdx.x >= off) ? buf[threadIdx.x - off] : 0;
        __syncthreads();
        val += t;
        buf[threadIdx.x] = val;
        __syncthreads();
    }
    if (i < NN) rowptr[i] = val - v;
    if (threadIdx.x == 255) blocksums[blockIdx.x] = val;
}

__global__ void count_scan2(int* __restrict__ blocksums, int* __restrict__ rowptr)
{
    __shared__ int buf[256];
    int v = (threadIdx.x < SCAN_BLOCKS) ? blocksums[threadIdx.x] : 0;
    int val = v;
    buf[threadIdx.x] = val;
    __syncthreads();
    for (int off = 1; off < 256; off <<= 1) {
        int t = (threadIdx.x >= off) ? buf[threadIdx.x - off] : 0;
        __syncthreads();
        val += t;
        buf[threadIdx.x] = val;
        __syncthreads();
    }
    if (threadIdx.x < SCAN_BLOCKS) blocksums[threadIdx.x] = val - v;
    if (threadIdx.x == 255) rowptr[NN] = val;
}

__global__ void count_scan3(const int* __restrict__ blocksums, int* __restrict__ rowptr,
                            int* __restrict__ cursor)
{
    int i = blockIdx.x * 256 + threadIdx.x;
    if (i < NN) {
        int r = rowptr[i] + blocksums[blockIdx.x];
        rowptr[i] = r;
        cursor[i] = r;
    }
}

__global__ void csr_fill_kernel(const int* __restrict__ ei, int* __restrict__ cursor,
                                int2* __restrict__ csr)
{
    int e = blockIdx.x * 256 + threadIdx.x;
    if (e >= EE) return;
    int dst = ei[EE + e];
    int pos = atomicAdd(&cursor[dst], 1);
    csr[pos] = make_int2(ei[e], e);     // {src, eid} one 8B store
}

// -------- per-node edge-attr sums + degree: s7[n][0..6], s7[n][7]=deg --------
__global__ __launch_bounds__(256) void node_prep_kernel(
    const float* __restrict__ ea, const int* __restrict__ rowptr,
    const int2* __restrict__ csr, float* __restrict__ s7)
{
    int n = blockIdx.x * 4 + (threadIdx.x >> 6);
    int lane = threadIdx.x & 63;
    if (n >= NN) return;
    int beg = rowptr[n], end = rowptr[n + 1];
    int j = lane >> 3, k = lane & 7;
    float s = 0.f;
    if (k < 7) {
        for (int base = beg; base < end; base += 8) {
            int e_i = base + j;
            if (e_i < end) s += ea[(size_t)csr[e_i].y * 7 + k];
        }
    }
    s += __shfl_xor(s, 8);
    s += __shfl_xor(s, 16);
    s += __shfl_xor(s, 32);
    if (lane < 7)      s7[n * 8 + lane] = s;
    else if (lane == 7) s7[n * 8 + 7] = (float)(end - beg);
}

// --------- aggregation v4: packed-f16 BN+ReLU+accumulate ---------
template<int APPLYBN>
__global__ __launch_bounds__(256) void aggregate_kernel(
    const _Float16* __restrict__ zin, const int* __restrict__ rowptr,
    const int2* __restrict__ csr, const float* __restrict__ s7,
    const float* __restrict__ We, const float* __restrict__ be,
    const float* __restrict__ sums, const float* __restrict__ gamma,
    const float* __restrict__ beta, _Float16* __restrict__ aggH)
{
    __shared__ float sWe[7 * DD];
    for (int i = threadIdx.x; i < 7 * DD; i += 256) sWe[i] = We[i];
    __syncthreads();
    const int lane = threadIdx.x & 63;
    const int li = lane & 15;               // 16 lanes per node
    const int n = blockIdx.x * 16 + ((threadIdx.x >> 6) << 2) + (lane >> 4);
    const int d0 = li * 8;                  // dims d0..d0+7
    f16x2 Ah[4], Ch[4];
    const f16x2 zero2 = {(_Float16)0.f, (_Float16)0.f};
    if (APPLYBN) {
        const float invN = 1.0f / NN;
#pragma unroll
        for (int q = 0; q < 4; q++) {
#pragma unroll
            for (int s = 0; s < 2; s++) {
                int d = d0 + 2 * q + s;
                float mu = sums[d] * invN;
                float var = fmaf(-mu, mu, sums[DD + d] * invN);
                float a = gamma[d] * rsqrtf(var + BN_EPS);
                float c = fmaf(-mu, a, beta[d]);
                Ah[q][s] = (_Float16)a;
                Ch[q][s] = (_Float16)c;
            }
        }
    }
    const uint4* z4 = (const uint4*)zin;    // row = 16 uint4 chunks
    int beg = rowptr[n], end = rowptr[n + 1];
    f16x2 acch[4] = {zero2, zero2, zero2, zero2};
#define ACCU(uu) { U32H2 p0, p1, p2, p3; \
    p0.u = (uu).x; p1.u = (uu).y; p2.u = (uu).z; p3.u = (uu).w; \
    if (APPLYBN) { \
        acch[0] += __builtin_elementwise_max(Ah[0] * p0.v + Ch[0], zero2); \
        acch[1] += __builtin_elementwise_max(Ah[1] * p1.v + Ch[1], zero2); \
        acch[2] += __builtin_elementwise_max(Ah[2] * p2.v + Ch[2], zero2); \
        acch[3] += __builtin_elementwise_max(Ah[3] * p3.v + Ch[3], zero2); \
    } else { \
        acch[0] += p0.v; acch[1] += p1.v; acch[2] += p2.v; acch[3] += p3.v; \
    } }
    int i = beg;
    for (; i + 8 <= end; i += 8) {
        uint4 u[8];
#pragma unroll
        for (int t = 0; t < 8; t++)
            u[t] = z4[(size_t)csr[i + t].x * 16 + li];
#pragma unroll
        for (int t = 0; t < 8; t++) ACCU(u[t])
    }
    for (; i + 4 <= end; i += 4) {
        uint4 u[4];
#pragma unroll
        for (int t = 0; t < 4; t++)
            u[t] = z4[(size_t)csr[i + t].x * 16 + li];
#pragma unroll
        for (int t = 0; t < 4; t++) ACCU(u[t])
    }
    for (; i < end; i++) {
        uint4 u = z4[(size_t)csr[i].x * 16 + li];
        ACCU(u)
    }
#undef ACCU
    float dg = s7[n * 8 + 7];
    float r[8];
#pragma unroll
    for (int q = 0; q < 4; q++) {
        r[2 * q]     = fmaf(dg, be[d0 + 2 * q],     (float)acch[q][0]);
        r[2 * q + 1] = fmaf(dg, be[d0 + 2 * q + 1], (float)acch[q][1]);
    }
#pragma unroll
    for (int k = 0; k < 7; k++) {
        float sv = s7[n * 8 + k];
#pragma unroll
        for (int t = 0; t < 8; t++) r[t] = fmaf(sv, sWe[k * DD + d0 + t], r[t]);
    }
    uint4 o;
    U32F16 p0, p1, p2, p3;
    p0.h[0] = (_Float16)r[0]; p0.h[1] = (_Float16)r[1];
    p1.h[0] = (_Float16)r[2]; p1.h[1] = (_Float16)r[3];
    p2.h[0] = (_Float16)r[4]; p2.h[1] = (_Float16)r[5];
    p3.h[0] = (_Float16)r[6]; p3.h[1] = (_Float16)r[7];
    o.x = p0.u; o.y = p1.u; o.z = p2.u; o.w = p3.u;
    ((uint4*)aggH)[(size_t)n * 16 + li] = o;
}

// ---------------- fused MLP v3f: 512 thr / 8 waves, 128 rows/block, grid=391 ----------------
// v3e + A-frag loads hoisted BEFORE the first barrier (latency rides the staging drain).
__global__ __launch_bounds__(512) void mlp_fused3(
    const _Float16* __restrict__ A, const char* __restrict__ W1T_l,
    const float* __restrict__ b1l, const char* __restrict__ W2T_l,
    const float* __restrict__ b2l, _Float16* __restrict__ Z,
    float* __restrict__ sums)
{
    __shared__ __align__(16) char W1s[65536];   // 256 rows x 256B, swz
    __shared__ __align__(16) char W2s[32768];   // 128 rows x 256B (one K-half), swz
    __shared__ __align__(16) char Hid[32768];   // 128 rows x 128 cols f16 (one half), swz
    __shared__ float red[8][2][128];
    const int tid = threadIdx.x, lane = tid & 63, wid = tid >> 6;   // 8 waves
    const int lr = lane & 15, kg = lane >> 4;
    const int rowA = blockIdx.x * 128 + wid * 16;

    // ---- upfront async staging: W1 full (8/wave) + W2 K-half0 (4/wave) ----
#pragma unroll
    for (int i = 0; i < 8; i++) {
        int chunk = wid * 8192 + i * 1024;
        __builtin_amdgcn_global_load_lds(
            (const __attribute__((address_space(1))) unsigned int*)(W1T_l + chunk + lane * 16),
            (__attribute__((address_space(3))) unsigned int*)(W1s + chunk),
            16, 0, 0);
    }
#pragma unroll
    for (int i = 0; i < 4; i++) {
        int chunk = wid * 4096 + i * 1024;
        __builtin_amdgcn_global_load_lds(
            (const __attribute__((address_space(1))) unsigned int*)(W2T_l + chunk + lane * 16),
            (__attribute__((address_space(3))) unsigned int*)(W2s + chunk),
            16, 0, 0);
    }

    // ---- A-frags issued BEFORE the barrier: latency hides under staging drain ----
    f16x8 a[4];
    const _Float16* Ap = A + (size_t)(rowA + lr) * DD + kg * 8;
#pragma unroll
    for (int ks = 0; ks < 4; ks++) a[ks] = *(const f16x8*)(Ap + ks * 32);

    __syncthreads();

    const int r = wid * 16 + lr;                 // hidden row (block-local)
    const int rswz = (r & 7) << 4;
    f32x4 acc2[8] = {};
#pragma unroll
    for (int h = 0; h < 2; h++) {
        // ---- GEMM1 half h (swapped operands): Hid[r][0..127] = relu(A @ W1h + b1h) ----
#pragma unroll
        for (int gq = 0; gq < 2; gq++) {
            f32x4 acc[4] = {};
#pragma unroll
            for (int ks = 0; ks < 4; ks++) {
#pragma unroll
                for (int g = 0; g < 4; g++) {
                    int row = h * 128 + gq * 64 + g * 16 + lr;
                    int byteo = (row * 256 + ks * 64 + kg * 16) ^ ((row & 7) << 4);
                    f16x8 b = *(const f16x8*)(W1s + byteo);
                    acc[g] = __builtin_amdgcn_mfma_f32_16x16x32_f16(b, a[ks], acc[g], 0, 0, 0);
                }
            }
#pragma unroll
            for (int g = 0; g < 4; g++) {
                int lcol = gq * 64 + g * 16 + kg * 4;      // col within half
                float4 bv = *(const float4*)(b1l + h * 128 + lcol);
                U32F16 p0, p1;
                p0.h[0] = (_Float16)fmaxf(acc[g][0] + bv.x, 0.f);
                p0.h[1] = (_Float16)fmaxf(acc[g][1] + bv.y, 0.f);
                p1.h[0] = (_Float16)fmaxf(acc[g][2] + bv.z, 0.f);
                p1.h[1] = (_Float16)fmaxf(acc[g][3] + bv.w, 0.f);
                int byteo = (r * 256 + lcol * 2) ^ rswz;
                uint2 w; w.x = p0.u; w.y = p1.u;
                *(uint2*)(Hid + byteo) = w;
            }
        }
        __syncthreads();   // Hid ready; (h==1) also drains W2-half1 staging

        // ---- GEMM2 partial-K: acc2 += Hid_h @ W2_Kh ----
#pragma unroll
        for (int ks = 0; ks < 4; ks++) {
            int hb = (r * 256 + ks * 64 + kg * 16) ^ rswz;
            f16x8 a2 = *(const f16x8*)(Hid + hb);
#pragma unroll
            for (int g = 0; g < 8; g++) {
                int row = g * 16 + lr;
                int wb = (row * 256 + ks * 64 + kg * 16) ^ ((row & 7) << 4);
                f16x8 b = *(const f16x8*)(W2s + wb);
                acc2[g] = __builtin_amdgcn_mfma_f32_16x16x32_f16(a2, b, acc2[g], 0, 0, 0);
            }
        }
        if (h == 0) {
            __syncthreads();   // GEMM2h0 done reading W2s + Hid
            // issue W2 K-half1 staging; flies under GEMM1-half1 (drained at its barrier)
#pragma unroll
            for (int i = 0; i < 4; i++) {
                int chunk = wid * 4096 + i * 1024;
                __builtin_amdgcn_global_load_lds(
                    (const __attribute__((address_space(1))) unsigned int*)(W2T_l + 32768 + chunk + lane * 16),
                    (__attribute__((address_space(3))) unsigned int*)(W2s + chunk),
                    16, 0, 0);
            }
        }
    }

    // ---- epilogue: bias, stats, direct f16 stores (no pack shfls) ----
    float sp[8] = {}, sq[8] = {};
#pragma unroll
    for (int g = 0; g < 8; g++) {
        int col = g * 16 + lr;
        float bv = b2l[col];
        int rbase = rowA + kg * 4;
#pragma unroll
        for (int j = 0; j < 4; j++) {
            float v = acc2[g][j] + bv;
            float keep = (rbase + j < NN) ? 1.f : 0.f;
            sp[g] = fmaf(v, keep, sp[g]);
            sq[g] = fmaf(v * v, keep, sq[g]);
            Z[(size_t)(rbase + j) * DD + col] = (_Float16)v;
        }
    }
#pragma unroll
    for (int g = 0; g < 8; g++) {
        sp[g] += __shfl_xor(sp[g], 16); sp[g] += __shfl_xor(sp[g], 32);
        sq[g] += __shfl_xor(sq[g], 16); sq[g] += __shfl_xor(sq[g], 32);
    }
    if (lane < 16) {
#pragma unroll
        for (int g = 0; g < 8; g++) {
            red[wid][0][g * 16 + lr] = sp[g];
            red[wid][1][g * 16 + lr] = sq[g];
        }
    }
    __syncthreads();
    if (tid < 128) {
        float s = 0.f, s2 = 0.f;
#pragma unroll
        for (int w = 0; w < 8; w++) { s += red[w][0][tid]; s2 += red[w][1][tid]; }
        atomicAdd(&sums[tid], s);
        atomicAdd(&sums[DD + tid], s2);
    }
}

// ---------------- f16 MFMA GEMM (projection only) ----------------
template<int K, int Nn>
__global__ __launch_bounds__(256) void gemm_f16(const _Float16* __restrict__ A,
    const _Float16* __restrict__ BT, const float* __restrict__ bias,
    _Float16* __restrict__ C)
{
    const int tid = threadIdx.x;
    const int lane = tid & 63, wid = tid >> 6;
    const int wm = wid >> 1, wn = wid & 1;
    const int row0 = blockIdx.x * 128 + wm * 64;
    const int col0 = blockIdx.y * 64 + wn * 32;
    const int lr = lane & 15, lk = (lane >> 4) * 8;
    f32x4 acc[4][2] = {};
    const _Float16* Ap = A + (size_t)(row0 + lr) * K + lk;
    const _Float16* Bp = BT + (size_t)(col0 + lr) * K + lk;
#pragma unroll
    for (int ks = 0; ks < K; ks += 32) {
        f16x8 a[4], b[2];
#pragma unroll
        for (int f = 0; f < 4; f++) a[f] = *(const f16x8*)(Ap + (size_t)f * 16 * K + ks);
#pragma unroll
        for (int g = 0; g < 2; g++) b[g] = *(const f16x8*)(Bp + (size_t)g * 16 * K + ks);
#pragma unroll
        for (int f = 0; f < 4; f++)
#pragma unroll
            for (int g = 0; g < 2; g++)
                acc[f][g] = __builtin_amdgcn_mfma_f32_16x16x32_f16(a[f], b[g], acc[f][g], 0, 0, 0);
    }
#pragma unroll
    for (int f = 0; f < 4; f++)
#pragma unroll
        for (int g = 0; g < 2; g++) {
            int col = col0 + g * 16 + lr;
            float bv = bias[col];
            int rbase = row0 + f * 16 + (lane >> 4) * 4;
#pragma unroll
            for (int j = 0; j < 4; j++)
                C[(size_t)(rbase + j) * Nn + col] = (_Float16)(acc[f][g][j] + bv);
        }
}

// ---------------- final BN apply -> f32 d_out ----------------
__global__ void bn_apply_kernel(const _Float16* __restrict__ z, const float* __restrict__ sums,
                                const float* __restrict__ gamma, const float* __restrict__ beta,
                                float* __restrict__ outF)
{
    int idx = blockIdx.x * 256 + threadIdx.x;   // over NN*64 u32 pairs
    if (idx >= NN * 64) return;
    int li = idx & 63;
    int d0 = 2 * li, d1 = d0 + 1;
    const float invN = 1.0f / NN;
    float mu0 = sums[d0] * invN, mu1 = sums[d1] * invN;
    float var0 = fmaf(-mu0, mu0, sums[DD + d0] * invN);
    float var1 = fmaf(-mu1, mu1, sums[DD + d1] * invN);
    float i0 = rsqrtf(var0 + BN_EPS), i1 = rsqrtf(var1 + BN_EPS);
    float a0 = gamma[d0] * i0, a1 = gamma[d1] * i1;
    float c0 = fmaf(-mu0, a0, beta[d0]), c1 = fmaf(-mu1, a1, beta[d1]);
    U32F16 u; u.u = ((const unsigned int*)z)[idx];
    int n = idx >> 6;
    float2 o = make_float2(fmaf(a0, (float)u.h[0], c0), fmaf(a1, (float)u.h[1], c1));
    *(float2*)(outF + (size_t)n * DD + d0) = o;
}

// ---------------------------------------------------------------------------
extern "C" void kernel_launch(void* const* d_in, const int* in_sizes, int n_in,
                              void* d_out, int out_size, void* d_ws, size_t ws_size,
                              hipStream_t stream)
{
    const float* x     = (const float*)d_in[0];
    const float* ea    = (const float*)d_in[1];
    const float* Wx    = (const float*)d_in[2];
    const float* bx    = (const float*)d_in[3];
    const float* We    = (const float*)d_in[4];
    const float* be    = (const float*)d_in[5];
    const float* W1    = (const float*)d_in[6];
    const float* b1    = (const float*)d_in[7];
    const float* W2    = (const float*)d_in[8];
    const float* b2    = (const float*)d_in[9];
    const float* gamma = (const float*)d_in[10];
    const float* beta  = (const float*)d_in[11];
    const int*   ei    = (const int*)d_in[12];

    // ---- workspace layout ----
    char* base = (char*)d_ws;
    size_t off = 0;
    auto alloc = [&](size_t bytes) { void* p = base + off; off += (bytes + 15) & ~(size_t)15; return p; };
    _Float16* h16  = (_Float16*)alloc((size_t)NPAD * DD * 2);   // proj output (layer-0 input)
    _Float16* aggH = (_Float16*)alloc((size_t)NPAD * DD * 2);
    _Float16* z16  = (_Float16*)alloc((size_t)NPAD * DD * 2);   // raw MLP output (pre-BN)
    _Float16* xH   = (_Float16*)alloc((size_t)NPAD * KX * 2);
    _Float16* WxT  = (_Float16*)alloc((size_t)DD * KX * 2);
    char*     W1T  = (char*)    alloc((size_t)LL * 65536);      // pre-swizzled LDS images
    char*     W2T  = (char*)    alloc((size_t)LL * 65536);      // 2 x 32KB K-half images/layer
    float*    s7   = (float*)   alloc((size_t)NN * 8 * 4);
    float*    sumsL= (float*)   alloc((size_t)LL * 256 * 4);    // per-layer BN sums
    int* counts    = (int*)alloc(50048 * 4);
    int* rowptr    = (int*)alloc(50056 * 4);
    int* cursor    = (int*)alloc(50048 * 4);
    int* blocksums = (int*)alloc(256 * 4);
    int2* csr      = (int2*)alloc((size_t)EE * 8);
    if (ws_size < off) return;

    // ---- prolog (prep fuses all conversions + zeroing) ----
    prep_kernel<<<(R5 + 255) / 256, 256, 0, stream>>>(
        x, Wx, W1, W2, xH, WxT, W1T, W2T, counts, sumsL, aggH);
    gemm_f16<KX, DD><<<dim3(NPAD / 128, DD / 64), 256, 0, stream>>>(xH, WxT, bx, h16);
    count_kernel<<<(EE + 255) / 256, 256, 0, stream>>>(ei, counts);
    count_scan1<<<SCAN_BLOCKS, 256, 0, stream>>>(counts, rowptr, blocksums);
    count_scan2<<<1, 256, 0, stream>>>(blocksums, rowptr);
    count_scan3<<<SCAN_BLOCKS, 256, 0, stream>>>(blocksums, rowptr, cursor);
    csr_fill_kernel<<<(EE + 255) / 256, 256, 0, stream>>>(ei, cursor, csr);
    node_prep_kernel<<<(NN + 3) / 4, 256, 0, stream>>>(ea, rowptr, csr, s7);

    // ---- layers ----
    for (int l = 0; l < LL; l++) {
        if (l == 0)
            aggregate_kernel<0><<<NN / 16, 256, 0, stream>>>(
                h16, rowptr, csr, s7, We, be, nullptr, nullptr, nullptr, aggH);
        else
            aggregate_kernel<1><<<NN / 16, 256, 0, stream>>>(
                z16, rowptr, csr, s7, We, be, sumsL + (size_t)(l - 1) * 256,
                gamma + (size_t)(l - 1) * DD, beta + (size_t)(l - 1) * DD, aggH);
        mlp_fused3<<<NPAD / 128, 512, 0, stream>>>(
            aggH, W1T + (size_t)l * 65536, b1 + (size_t)l * HH,
            W2T + (size_t)l * 65536, b2 + (size_t)l * DD, z16,
            sumsL + (size_t)l * 256);
    }
    bn_apply_kernel<<<(NN * 64 + 255) / 256, 256, 0, stream>>>(
        z16, sumsL + (size_t)(LL - 1) * 256, gamma + (size_t)(LL - 1) * DD,
        beta + (size_t)(LL - 1) * DD, (float*)d_out);
}